// Round 10
// baseline (164.163 us; speedup 1.0000x reference)
//
#include <hip/hip_runtime.h>

#define N_SEQ 4096
#define N_FFT 8192
#define LAYERS 3
#define FT 512                 // threads per FFT block
#define PIDX(i) ((i) + ((i) >> 5))   // +1 word per 32 -> all passes 2-way (free)

// =============== radix-16 pass: two DIF stages (M then M/4) in registers ===============
template<int M>
__device__ inline void pass16_fwd(float* re, float* im, int tid)
{
    const int Q = M >> 4;
    const int j = tid & (Q - 1);
    const int G = tid / Q;
    const int base = G * M + j;
    const float KR[4] = {1.f, 0.9238795325f, 0.7071067812f, 0.3826834324f};
    const float KI[4] = {0.f, -0.3826834324f, -0.7071067812f, -0.9238795325f};
    float xr[4][4], xi[4][4];
#pragma unroll
    for (int a = 0; a < 4; ++a)
#pragma unroll
        for (int b = 0; b < 4; ++b) {
            int idx = PIDX(base + a * (M >> 2) + b * Q);
            xr[a][b] = re[idx]; xi[a][b] = im[idx];
        }
    float cj, sj;
    __sincosf(-6.283185307179586f / (float)M * (float)j, &sj, &cj);
#pragma unroll
    for (int b = 0; b < 4; ++b) {
        float c1 = cj * KR[b] - sj * KI[b];
        float s1 = cj * KI[b] + sj * KR[b];
        float c2 = c1 * c1 - s1 * s1, s2 = 2.f * c1 * s1;
        float c3 = c2 * c1 - s2 * s1, s3 = c2 * s1 + s2 * c1;
        float ar = xr[0][b] + xr[2][b], ai = xi[0][b] + xi[2][b];
        float br = xr[0][b] - xr[2][b], bi = xi[0][b] - xi[2][b];
        float cr = xr[1][b] + xr[3][b], ci = xi[1][b] + xi[3][b];
        float dr = xi[1][b] - xi[3][b], di = -(xr[1][b] - xr[3][b]);
        xr[0][b] = ar + cr;               xi[0][b] = ai + ci;
        float t1r = br + dr, t1i = bi + di;
        xr[1][b] = t1r * c1 - t1i * s1;   xi[1][b] = t1r * s1 + t1i * c1;
        float t2r = ar - cr, t2i = ai - ci;
        xr[2][b] = t2r * c2 - t2i * s2;   xi[2][b] = t2r * s2 + t2i * c2;
        float t3r = br - dr, t3i = bi - di;
        xr[3][b] = t3r * c3 - t3i * s3;   xi[3][b] = t3r * s3 + t3i * c3;
    }
    {
        float e1c = cj * cj - sj * sj, e1s = 2.f * cj * sj;      // W^{2j}
        float c1 = e1c * e1c - e1s * e1s, s1 = 2.f * e1c * e1s;  // W^{4j}
        float c2 = c1 * c1 - s1 * s1, s2 = 2.f * c1 * s1;
        float c3 = c2 * c1 - s2 * s1, s3 = c2 * s1 + s2 * c1;
#pragma unroll
        for (int a = 0; a < 4; ++a) {
            float ar = xr[a][0] + xr[a][2], ai = xi[a][0] + xi[a][2];
            float br = xr[a][0] - xr[a][2], bi = xi[a][0] - xi[a][2];
            float cr = xr[a][1] + xr[a][3], ci = xi[a][1] + xi[a][3];
            float dr = xi[a][1] - xi[a][3], di = -(xr[a][1] - xr[a][3]);
            xr[a][0] = ar + cr;               xi[a][0] = ai + ci;
            float t1r = br + dr, t1i = bi + di;
            xr[a][1] = t1r * c1 - t1i * s1;   xi[a][1] = t1r * s1 + t1i * c1;
            float t2r = ar - cr, t2i = ai - ci;
            xr[a][2] = t2r * c2 - t2i * s2;   xi[a][2] = t2r * s2 + t2i * c2;
            float t3r = br - dr, t3i = bi - di;
            xr[a][3] = t3r * c3 - t3i * s3;   xi[a][3] = t3r * s3 + t3i * c3;
        }
    }
#pragma unroll
    for (int a = 0; a < 4; ++a)
#pragma unroll
        for (int b = 0; b < 4; ++b) {
            int idx = PIDX(base + a * (M >> 2) + b * Q);
            re[idx] = xr[a][b]; im[idx] = xi[a][b];
        }
}

template<int M>
__device__ inline void pass16_inv(float* re, float* im, int tid)
{
    const int Q = M >> 4;
    const int j = tid & (Q - 1);
    const int G = tid / Q;
    const int base = G * M + j;
    const float KR[4] = {1.f, 0.9238795325f, 0.7071067812f, 0.3826834324f};
    const float KI[4] = {0.f, 0.3826834324f, 0.7071067812f, 0.9238795325f};   // conj
    float xr[4][4], xi[4][4];
#pragma unroll
    for (int a = 0; a < 4; ++a)
#pragma unroll
        for (int b = 0; b < 4; ++b) {
            int idx = PIDX(base + a * (M >> 2) + b * Q);
            xr[a][b] = re[idx]; xi[a][b] = im[idx];
        }
    float cj, sj;
    __sincosf(6.283185307179586f / (float)M * (float)j, &sj, &cj);
    {
        float e1c = cj * cj - sj * sj, e1s = 2.f * cj * sj;
        float c1 = e1c * e1c - e1s * e1s, s1 = 2.f * e1c * e1s;
        float c2 = c1 * c1 - s1 * s1, s2 = 2.f * c1 * s1;
        float c3 = c2 * c1 - s2 * s1, s3 = c2 * s1 + s2 * c1;
#pragma unroll
        for (int a = 0; a < 4; ++a) {
            float t0r = xr[a][0], t0i = xi[a][0];
            float t1r = xr[a][1] * c1 - xi[a][1] * s1, t1i = xr[a][1] * s1 + xi[a][1] * c1;
            float t2r = xr[a][2] * c2 - xi[a][2] * s2, t2i = xr[a][2] * s2 + xi[a][2] * c2;
            float t3r = xr[a][3] * c3 - xi[a][3] * s3, t3i = xr[a][3] * s3 + xi[a][3] * c3;
            float pr = t0r + t2r, pi = t0i + t2i;
            float qr = t0r - t2r, qi = t0i - t2i;
            float rr = t1r + t3r, ri = t1i + t3i;
            float sr = -(t1i - t3i), si = t1r - t3r;
            xr[a][0] = pr + rr; xi[a][0] = pi + ri;
            xr[a][1] = qr + sr; xi[a][1] = qi + si;
            xr[a][2] = pr - rr; xi[a][2] = pi - ri;
            xr[a][3] = qr - sr; xi[a][3] = qi - si;
        }
    }
#pragma unroll
    for (int b = 0; b < 4; ++b) {
        float c1 = cj * KR[b] - sj * KI[b];
        float s1 = cj * KI[b] + sj * KR[b];
        float c2 = c1 * c1 - s1 * s1, s2 = 2.f * c1 * s1;
        float c3 = c2 * c1 - s2 * s1, s3 = c2 * s1 + s2 * c1;
        float t0r = xr[0][b], t0i = xi[0][b];
        float t1r = xr[1][b] * c1 - xi[1][b] * s1, t1i = xr[1][b] * s1 + xi[1][b] * c1;
        float t2r = xr[2][b] * c2 - xi[2][b] * s2, t2i = xr[2][b] * s2 + xi[2][b] * c2;
        float t3r = xr[3][b] * c3 - xi[3][b] * s3, t3i = xr[3][b] * s3 + xi[3][b] * c3;
        float pr = t0r + t2r, pi = t0i + t2i;
        float qr = t0r - t2r, qi = t0i - t2i;
        float rr = t1r + t3r, ri = t1i + t3i;
        float sr = -(t1i - t3i), si = t1r - t3r;
        xr[0][b] = pr + rr; xi[0][b] = pi + ri;
        xr[1][b] = qr + sr; xi[1][b] = qi + si;
        xr[2][b] = pr - rr; xi[2][b] = pi - ri;
        xr[3][b] = qr - sr; xi[3][b] = qi - si;
    }
#pragma unroll
    for (int a = 0; a < 4; ++a)
#pragma unroll
        for (int b = 0; b < 4; ++b) {
            int idx = PIDX(base + a * (M >> 2) + b * Q);
            re[idx] = xr[a][b]; im[idx] = xi[a][b];
        }
}

// ======= radix-8 tail (stage m=8 + r2), contiguous 8 points, constant twiddles =======
__device__ inline void fwd8(float* zr, float* zi, int o)
{
    const float R = 0.70710678118654752f;
    {
        float ar = zr[o] + zr[o+4], ai = zi[o] + zi[o+4];
        float br = zr[o] - zr[o+4], bi = zi[o] - zi[o+4];
        float cr = zr[o+2] + zr[o+6], ci = zi[o+2] + zi[o+6];
        float dr = zi[o+2] - zi[o+6], di = -(zr[o+2] - zr[o+6]);
        zr[o]   = ar + cr; zi[o]   = ai + ci;
        zr[o+2] = br + dr; zi[o+2] = bi + di;
        zr[o+4] = ar - cr; zi[o+4] = ai - ci;
        zr[o+6] = br - dr; zi[o+6] = bi - di;
    }
    {
        float ar = zr[o+1] + zr[o+5], ai = zi[o+1] + zi[o+5];
        float br = zr[o+1] - zr[o+5], bi = zi[o+1] - zi[o+5];
        float cr = zr[o+3] + zr[o+7], ci = zi[o+3] + zi[o+7];
        float dr = zi[o+3] - zi[o+7], di = -(zr[o+3] - zr[o+7]);
        zr[o+1] = ar + cr; zi[o+1] = ai + ci;
        float t1r = br + dr, t1i = bi + di;
        zr[o+3] = R * (t1r + t1i); zi[o+3] = R * (t1i - t1r);
        float t2r = ar - cr, t2i = ai - ci;
        zr[o+5] = t2i;  zi[o+5] = -t2r;
        float t3r = br - dr, t3i = bi - di;
        zr[o+7] = R * (t3i - t3r); zi[o+7] = -R * (t3r + t3i);
    }
#pragma unroll
    for (int p = 0; p < 8; p += 2) {
        float ur = zr[o+p], ui = zi[o+p], vr = zr[o+p+1], vi = zi[o+p+1];
        zr[o+p]   = ur + vr; zi[o+p]   = ui + vi;
        zr[o+p+1] = ur - vr; zi[o+p+1] = ui - vi;
    }
}

__device__ inline void inv8(float* zr, float* zi, int o)
{
    const float R = 0.70710678118654752f;
#pragma unroll
    for (int p = 0; p < 8; p += 2) {
        float ur = zr[o+p], ui = zi[o+p], vr = zr[o+p+1], vi = zi[o+p+1];
        zr[o+p]   = ur + vr; zi[o+p]   = ui + vi;
        zr[o+p+1] = ur - vr; zi[o+p+1] = ui - vi;
    }
    {
        float t0r = zr[o],   t0i = zi[o];
        float t1r = zr[o+2], t1i = zi[o+2];
        float t2r = zr[o+4], t2i = zi[o+4];
        float t3r = zr[o+6], t3i = zi[o+6];
        float pr = t0r + t2r, pi = t0i + t2i;
        float qr = t0r - t2r, qi = t0i - t2i;
        float rr = t1r + t3r, ri = t1i + t3i;
        float sr = -(t1i - t3i), si = t1r - t3r;
        zr[o]   = pr + rr; zi[o]   = pi + ri;
        zr[o+2] = qr + sr; zi[o+2] = qi + si;
        zr[o+4] = pr - rr; zi[o+4] = pi - ri;
        zr[o+6] = qr - sr; zi[o+6] = qi - si;
    }
    {
        float t0r = zr[o+1], t0i = zi[o+1];
        float yr = zr[o+3], yi = zi[o+3];
        float t1r = R * (yr - yi), t1i = R * (yr + yi);
        yr = zr[o+5]; yi = zi[o+5];
        float t2r = -yi, t2i = yr;
        yr = zr[o+7]; yi = zi[o+7];
        float t3r = -R * (yr + yi), t3i = R * (yr - yi);
        float pr = t0r + t2r, pi = t0i + t2i;
        float qr = t0r - t2r, qi = t0i - t2i;
        float rr = t1r + t3r, ri = t1i + t3i;
        float sr = -(t1i - t3i), si = t1r - t3r;
        zr[o+1] = pr + rr; zi[o+1] = pi + ri;
        zr[o+3] = qr + sr; zi[o+3] = qi + si;
        zr[o+5] = pr - rr; zi[o+5] = pi - ri;
        zr[o+7] = qr - sr; zi[o+7] = qi - si;
    }
}

// ============ prep: [blocks 0..127] RPE (64 pos) -> a_t
//              [blocks 128..639] transpose x -> xt2 ============
// LESSONS R6-R9: (a) 4 SIMDs of VALU share ONE LDS pipe -> activations via LDS
// b128, weights via VMEM/L1-L2 (separate pipe); (b) compiler won't form
// SGPR-weight fma from pointers and spills big acc arrays under tight caps ->
// plain register blocking + launch_bounds(256,2) (cap 256, no squeeze).
// Hidden: thread = 4pos x 4feat (acc 16). Out: thread = 8pos x 8out (acc 64);
// per j per wave: 2 LDS b128 (24 cyc) per 64 fma-inst (32 CU-VALU cyc) -> VALU-bound.
__global__ __launch_bounds__(256, 2) void prep_kernel(
    const float* __restrict__ x,
    const float* __restrict__ w_in, const float* __restrict__ b_in,
    const float* __restrict__ w_hid, const float* __restrict__ b_hid,
    const float* __restrict__ w_out, const float* __restrict__ b_out,
    float* __restrict__ a_t, float2* __restrict__ xt2)
{
    __shared__ __align__(16) char smem[33536];
    const int tid = threadIdx.x;

    if (blockIdx.x >= 128) {
        // ---- transpose x: (2,8,N,64) -> xt2[hd][n] = (x_b0, x_b1) ----
        float (*t0)[65] = (float (*)[65])smem;
        float (*t1)[65] = (float (*)[65])(smem + 16640);
        int bb = blockIdx.x - 128;
        int h = bb >> 6;
        int nb = bb & 63;
        int lx = tid & 63;
        int ly = tid >> 6;          // 0..3
        const float* s0 = x + ((size_t)h * N_SEQ + nb * 64) * 64;
        const float* s1 = x + ((size_t)(8 + h) * N_SEQ + nb * 64) * 64;
        for (int r = ly; r < 64; r += 4) {
            t0[r][lx] = s0[r * 64 + lx];
            t1[r][lx] = s1[r * 64 + lx];
        }
        __syncthreads();
        for (int r = ly; r < 64; r += 4) {
            float2* dst = xt2 + (size_t)(h * 64 + r) * N_SEQ + nb * 64;
            dst[lx] = make_float2(t0[lx][r], t1[lx][r]);
        }
        return;
    }

    // LDS: ubuf[j=64][pos stride 68] transposed activations; sums[fq=16][68]
    float (*ubuf)[68] = (float (*)[68])smem;                       // 17408 B
    float (*sums)[68] = (float (*)[68])(smem + 17408);             //  4352 B
    const int pos0 = blockIdx.x * 64;

    // ---- hidden chain: thread = (pq = tid&15 -> 4 pos, fq = tid>>4 -> 4 feats) ----
    {
        const int pq = tid & 15;
        const int fq = tid >> 4;
        float v[4];
#pragma unroll
        for (int k = 0; k < 4; ++k) {
            int pos = pos0 + pq * 4 + k;
            if (pos == 0 || pos == N_SEQ) v[k] = 1.0f;
            else if (pos < N_SEQ)         v[k] = 1.0f / (float)(pos + 1);
            else                          v[k] = -1.0f / (float)(2 * N_SEQ + 1 - pos);
        }
        float h[4][4];   // [feat i][pos k]
#pragma unroll
        for (int i = 0; i < 4; ++i) {
            float wi = w_in[fq * 4 + i], bi = b_in[fq * 4 + i];
#pragma unroll
            for (int k = 0; k < 4; ++k) h[i][k] = v[k] * wi + bi;
        }
        for (int L = 0; L <= LAYERS; ++L) {
            // RMS partials: ss[k] over this thread's 4 feats
            float4 ss = make_float4(0.f, 0.f, 0.f, 0.f);
#pragma unroll
            for (int i = 0; i < 4; ++i) {
                ss.x += h[i][0] * h[i][0]; ss.y += h[i][1] * h[i][1];
                ss.z += h[i][2] * h[i][2]; ss.w += h[i][3] * h[i][3];
            }
            *(float4*)&sums[fq][pq * 4] = ss;
            __syncthreads();      // also orders prior GEMM's ubuf reads
            float4 tot = make_float4(0.f, 0.f, 0.f, 0.f);
#pragma unroll
            for (int g = 0; g < 16; ++g) {
                float4 s4 = *(const float4*)&sums[g][pq * 4];
                tot.x += s4.x; tot.y += s4.y; tot.z += s4.z; tot.w += s4.w;
            }
            float r[4] = {rsqrtf(tot.x * (1.f/64.f) + 1e-8f),
                          rsqrtf(tot.y * (1.f/64.f) + 1e-8f),
                          rsqrtf(tot.z * (1.f/64.f) + 1e-8f),
                          rsqrtf(tot.w * (1.f/64.f) + 1e-8f)};
#pragma unroll
            for (int i = 0; i < 4; ++i) {
                float4 u4;
                u4.x = fmaxf(h[i][0] * r[0], 0.f);
                u4.y = fmaxf(h[i][1] * r[1], 0.f);
                u4.z = fmaxf(h[i][2] * r[2], 0.f);
                u4.w = fmaxf(h[i][3] * r[3], 0.f);
                *(float4*)&ubuf[fq * 4 + i][pq * 4] = u4;   // transposed [j][pos]
            }
            __syncthreads();
            if (L == LAYERS) break;   // final activation now in ubuf
            // GEMM: h_new = u @ W_L + b_L   (u from LDS b128, w from L1 VMEM)
            float acc[4][4];
#pragma unroll
            for (int i = 0; i < 4; ++i) {
                float bi = b_hid[L * 64 + fq * 4 + i];
#pragma unroll
                for (int k = 0; k < 4; ++k) acc[i][k] = bi;
            }
            const float* wb = w_hid + L * 4096 + fq * 4;
#pragma unroll 4
            for (int j = 0; j < 64; ++j) {
                float4 u4 = *(const float4*)&ubuf[j][pq * 4];
                float4 w4 = *(const float4*)(wb + j * 64);
                acc[0][0] = fmaf(u4.x, w4.x, acc[0][0]); acc[0][1] = fmaf(u4.y, w4.x, acc[0][1]);
                acc[0][2] = fmaf(u4.z, w4.x, acc[0][2]); acc[0][3] = fmaf(u4.w, w4.x, acc[0][3]);
                acc[1][0] = fmaf(u4.x, w4.y, acc[1][0]); acc[1][1] = fmaf(u4.y, w4.y, acc[1][1]);
                acc[1][2] = fmaf(u4.z, w4.y, acc[1][2]); acc[1][3] = fmaf(u4.w, w4.y, acc[1][3]);
                acc[2][0] = fmaf(u4.x, w4.z, acc[2][0]); acc[2][1] = fmaf(u4.y, w4.z, acc[2][1]);
                acc[2][2] = fmaf(u4.z, w4.z, acc[2][2]); acc[2][3] = fmaf(u4.w, w4.z, acc[2][3]);
                acc[3][0] = fmaf(u4.x, w4.w, acc[3][0]); acc[3][1] = fmaf(u4.y, w4.w, acc[3][1]);
                acc[3][2] = fmaf(u4.z, w4.w, acc[3][2]); acc[3][3] = fmaf(u4.w, w4.w, acc[3][3]);
            }
#pragma unroll
            for (int i = 0; i < 4; ++i)
#pragma unroll
                for (int k = 0; k < 4; ++k) h[i][k] = acc[i][k];
            // no sync here: next iteration's sums-write + sync orders ubuf reads
        }
    }

    // ---- out GEMM: wave wv handles chunks c = r*4 + wv; lane = (fo,po) ----
    {
        const int wv = tid >> 6;          // 0..3
        const int lane = tid & 63;
        const int po = lane & 7;          // 8 positions po*8..
        const int fo = lane >> 3;         // 8 outputs fo*8..
        for (int rnd = 0; rnd < 2; ++rnd) {
            const int c = rnd * 4 + wv;
            float acc[8][8];              // [out i][pos k]
#pragma unroll
            for (int i = 0; i < 8; ++i) {
                float bo = b_out[c * 64 + fo * 8 + i];
#pragma unroll
                for (int k = 0; k < 8; ++k) acc[i][k] = bo;
            }
            const float* wb = w_out + c * 64 + fo * 8;
#pragma unroll 2
            for (int j = 0; j < 64; ++j) {
                float4 u0 = *(const float4*)&ubuf[j][po * 8];
                float4 u1 = *(const float4*)&ubuf[j][po * 8 + 4];
                float4 w0 = *(const float4*)(wb + j * 512);
                float4 w1 = *(const float4*)(wb + j * 512 + 4);
                float wv_[8] = {w0.x, w0.y, w0.z, w0.w, w1.x, w1.y, w1.z, w1.w};
                float uv_[8] = {u0.x, u0.y, u0.z, u0.w, u1.x, u1.y, u1.z, u1.w};
#pragma unroll
                for (int i = 0; i < 8; ++i)
#pragma unroll
                    for (int k = 0; k < 8; ++k)
                        acc[i][k] = fmaf(uv_[k], wv_[i], acc[i][k]);
            }
#pragma unroll
            for (int i = 0; i < 8; ++i) {
                float* dst = a_t + (size_t)(c * 64 + fo * 8 + i) * N_FFT + pos0 + po * 8;
                *(float4*)dst       = make_float4(acc[i][0], acc[i][1], acc[i][2], acc[i][3]);
                *(float4*)(dst + 4) = make_float4(acc[i][4], acc[i][5], acc[i][6], acc[i][7]);
            }
        }
    }
}

// ========== conv: A-FFT (spectrum kept in regs) + z-FFT + mult + iFFT ==========
__global__ __launch_bounds__(FT, 2) void conv_kernel(const float* __restrict__ a_t,
                                                     const float2* __restrict__ xt2,
                                                     float2* __restrict__ out_t2)
{
    __shared__ float re[8448];
    __shared__ float im[8448];
    const int tid = threadIdx.x;
    const int hd = blockIdx.x;
    const float JR = 0.9238795325f;        // e^{-2pi i/16}
    const float JI = -0.3826834324f;

    // ---- A forward: fused m=8192 stage (real input) ----
    {
        const float* src = a_t + (size_t)hd * N_FFT;
        float ck, sk;
        __sincosf(-6.283185307179586f / 8192.f * (float)tid, &sk, &ck);
#pragma unroll
        for (int pp = 0; pp < 4; ++pp) {
            int k = pp * FT + tid;
            float x0 = src[k], x1 = src[k + 2048], x2 = src[k + 4096], x3 = src[k + 6144];
            float ar = x0 + x2, br = x0 - x2;
            float cr = x1 + x3, e = x1 - x3;
            re[PIDX(k)] = ar + cr; im[PIDX(k)] = 0.f;
            float c1 = ck, s1 = sk;
            float c2 = c1 * c1 - s1 * s1, s2 = 2.f * c1 * s1;
            float c3 = c2 * c1 - s2 * s1, s3 = c2 * s1 + s2 * c1;
            re[PIDX(k + 2048)] = br * c1 + e * s1;  im[PIDX(k + 2048)] = br * s1 - e * c1;
            float t2r = ar - cr;
            re[PIDX(k + 4096)] = t2r * c2;          im[PIDX(k + 4096)] = t2r * s2;
            re[PIDX(k + 6144)] = br * c3 - e * s3;  im[PIDX(k + 6144)] = br * s3 + e * c3;
            float tc = ck * JR - sk * JI; sk = ck * JI + sk * JR; ck = tc;  // W^{k+512}
        }
    }
    __syncthreads();
    pass16_fwd<2048>(re, im, tid);
    __syncthreads();
    pass16_fwd<128>(re, im, tid);
    __syncthreads();
    // ---- A tail: unscaled spectrum stays in registers (1/N folded in later) ----
    float afr[16], afi[16];
    {
        const int base = tid * 16;
#pragma unroll
        for (int c = 0; c < 16; ++c) { int idx = PIDX(base + c); afr[c] = re[idx]; afi[c] = im[idx]; }
        fwd8(afr, afi, 0); fwd8(afr, afi, 8);
    }
    __syncthreads();
    // ---- Z forward: fused m=8192 stage (packed complex, x2=x3=0) ----
    {
        const float2* src = xt2 + (size_t)hd * N_SEQ;
        float ck, sk;
        __sincosf(-6.283185307179586f / 8192.f * (float)tid, &sk, &ck);
#pragma unroll
        for (int pp = 0; pp < 4; ++pp) {
            int k = pp * FT + tid;
            float2 z0 = src[k], z1 = src[k + 2048];
            float ar = z0.x, ai = z0.y;
            float cr = z1.x, ci = z1.y;
            float dr = z1.y, di = -z1.x;
            re[PIDX(k)] = ar + cr; im[PIDX(k)] = ai + ci;
            float c1 = ck, s1 = sk;
            float c2 = c1 * c1 - s1 * s1, s2 = 2.f * c1 * s1;
            float c3 = c2 * c1 - s2 * s1, s3 = c2 * s1 + s2 * c1;
            float t1r = ar + dr, t1i = ai + di;
            re[PIDX(k + 2048)] = t1r * c1 - t1i * s1; im[PIDX(k + 2048)] = t1r * s1 + t1i * c1;
            float t2r = ar - cr, t2i = ai - ci;
            re[PIDX(k + 4096)] = t2r * c2 - t2i * s2; im[PIDX(k + 4096)] = t2r * s2 + t2i * c2;
            float t3r = ar - dr, t3i = ai - di;
            re[PIDX(k + 6144)] = t3r * c3 - t3i * s3; im[PIDX(k + 6144)] = t3r * s3 + t3i * c3;
            float tc = ck * JR - sk * JI; sk = ck * JI + sk * JR; ck = tc;
        }
    }
    __syncthreads();
    pass16_fwd<2048>(re, im, tid);
    __syncthreads();
    pass16_fwd<128>(re, im, tid);
    __syncthreads();
    {   // Z tail + pointwise (af in regs, 1/N fused) + inverse head
        const int base = tid * 16;
        float zr[16], zi[16];
#pragma unroll
        for (int c = 0; c < 16; ++c) { int idx = PIDX(base + c); zr[c] = re[idx]; zi[c] = im[idx]; }
        fwd8(zr, zi, 0); fwd8(zr, zi, 8);
        const float inv = 1.0f / (float)N_FFT;
#pragma unroll
        for (int c = 0; c < 16; ++c) {
            float xr = zr[c], xi_ = zi[c];
            zr[c] = (xr * afr[c] - xi_ * afi[c]) * inv;
            zi[c] = (xr * afi[c] + xi_ * afr[c]) * inv;
        }
        inv8(zr, zi, 0); inv8(zr, zi, 8);
#pragma unroll
        for (int c = 0; c < 16; ++c) { int idx = PIDX(base + c); re[idx] = zr[c]; im[idx] = zi[c]; }
    }
    __syncthreads();
    pass16_inv<128>(re, im, tid);
    __syncthreads();
    pass16_inv<2048>(re, im, tid);
    __syncthreads();
    {   // fused final inverse stage (m=8192): store only [0,4096)
        float2* dst = out_t2 + (size_t)hd * N_SEQ;
        float ck, sk;
        __sincosf(6.283185307179586f / 8192.f * (float)tid, &sk, &ck);
        const float JcR = 0.9238795325f, JcI = 0.3826834324f;
#pragma unroll
        for (int pp = 0; pp < 4; ++pp) {
            int k = pp * FT + tid;
            float c1 = ck, s1 = sk;
            float c2 = c1 * c1 - s1 * s1, s2 = 2.f * c1 * s1;
            float c3 = c2 * c1 - s2 * s1, s3 = c2 * s1 + s2 * c1;
            float t0r = re[PIDX(k)],        t0i = im[PIDX(k)];
            float y1r = re[PIDX(k + 2048)], y1i = im[PIDX(k + 2048)];
            float y2r = re[PIDX(k + 4096)], y2i = im[PIDX(k + 4096)];
            float y3r = re[PIDX(k + 6144)], y3i = im[PIDX(k + 6144)];
            float t1r = y1r * c1 - y1i * s1, t1i = y1r * s1 + y1i * c1;
            float t2r = y2r * c2 - y2i * s2, t2i = y2r * s2 + y2i * c2;
            float t3r = y3r * c3 - y3i * s3, t3i = y3r * s3 + y3i * c3;
            float pr = t0r + t2r, pi = t0i + t2i;
            float qr = t0r - t2r, qi = t0i - t2i;
            float rr = t1r + t3r, ri = t1i + t3i;
            float sr = -(t1i - t3i), si = t1r - t3r;
            dst[k]        = make_float2(pr + rr, pi + ri);
            dst[k + 2048] = make_float2(qr + sr, qi + si);
            float tc = ck * JcR - sk * JcI; sk = ck * JcI + sk * JcR; ck = tc;
        }
    }
}

// ========== transpose out: out_t2[hd][n] -> out (2,8,N,64) ==========
__global__ __launch_bounds__(256) void transpose_o_kernel(const float2* __restrict__ out_t2,
                                                          float* __restrict__ out)
{
    __shared__ float t0[64][65];
    __shared__ float t1[64][65];
    int h = blockIdx.x >> 6;
    int nb = blockIdx.x & 63;
    int lx = threadIdx.x & 63;
    int ly = threadIdx.x >> 6;
    for (int r = ly; r < 64; r += 4) {
        float2 v = out_t2[(size_t)(h * 64 + r) * N_SEQ + nb * 64 + lx];
        t0[r][lx] = v.x;
        t1[r][lx] = v.y;
    }
    __syncthreads();
    float* d0 = out + ((size_t)h * N_SEQ + nb * 64) * 64;
    float* d1 = out + ((size_t)(8 + h) * N_SEQ + nb * 64) * 64;
    for (int r = ly; r < 64; r += 4) {
        d0[r * 64 + lx] = t0[lx][r];
        d1[r * 64 + lx] = t1[lx][r];
    }
}

extern "C" void kernel_launch(void* const* d_in, const int* in_sizes, int n_in,
                              void* d_out, int out_size, void* d_ws, size_t ws_size,
                              hipStream_t stream)
{
    const float* x     = (const float*)d_in[0];
    const float* w_in  = (const float*)d_in[1];
    const float* b_in  = (const float*)d_in[2];
    const float* w_hid = (const float*)d_in[3];
    const float* b_hid = (const float*)d_in[4];
    const float* w_out = (const float*)d_in[5];
    const float* b_out = (const float*)d_in[6];
    float* out = (float*)d_out;

    char* ws = (char*)d_ws;
    float2* xt2    = (float2*)ws;                               // 16 MB
    float*  a_t    = (float*)(ws + (size_t)16 * 1024 * 1024);   // 16 MB
    float2* out_t2 = (float2*)(ws + (size_t)32 * 1024 * 1024);  // 16 MB

    prep_kernel<<<640, 256, 0, stream>>>(x, w_in, b_in, w_hid, b_hid, w_out, b_out,
                                         a_t, xt2);
    conv_kernel<<<512, FT, 0, stream>>>(a_t, xt2, out_t2);
    transpose_o_kernel<<<512, 256, 0, stream>>>(out_t2, out);
}

// Round 11
// 159.529 us; speedup vs baseline: 1.0290x; 1.0290x over previous
//
#include <hip/hip_runtime.h>

#define N_SEQ 4096
#define N_FFT 8192
#define LAYERS 3
#define FT 512                 // threads per FFT block
#define PIDX(i) ((i) + ((i) >> 5))   // +1 word per 32 -> all passes 2-way (free)

// =============== radix-16 pass: two DIF stages (M then M/4) in registers ===============
template<int M>
__device__ inline void pass16_fwd(float* re, float* im, int tid)
{
    const int Q = M >> 4;
    const int j = tid & (Q - 1);
    const int G = tid / Q;
    const int base = G * M + j;
    const float KR[4] = {1.f, 0.9238795325f, 0.7071067812f, 0.3826834324f};
    const float KI[4] = {0.f, -0.3826834324f, -0.7071067812f, -0.9238795325f};
    float xr[4][4], xi[4][4];
#pragma unroll
    for (int a = 0; a < 4; ++a)
#pragma unroll
        for (int b = 0; b < 4; ++b) {
            int idx = PIDX(base + a * (M >> 2) + b * Q);
            xr[a][b] = re[idx]; xi[a][b] = im[idx];
        }
    float cj, sj;
    __sincosf(-6.283185307179586f / (float)M * (float)j, &sj, &cj);
#pragma unroll
    for (int b = 0; b < 4; ++b) {
        float c1 = cj * KR[b] - sj * KI[b];
        float s1 = cj * KI[b] + sj * KR[b];
        float c2 = c1 * c1 - s1 * s1, s2 = 2.f * c1 * s1;
        float c3 = c2 * c1 - s2 * s1, s3 = c2 * s1 + s2 * c1;
        float ar = xr[0][b] + xr[2][b], ai = xi[0][b] + xi[2][b];
        float br = xr[0][b] - xr[2][b], bi = xi[0][b] - xi[2][b];
        float cr = xr[1][b] + xr[3][b], ci = xi[1][b] + xi[3][b];
        float dr = xi[1][b] - xi[3][b], di = -(xr[1][b] - xr[3][b]);
        xr[0][b] = ar + cr;               xi[0][b] = ai + ci;
        float t1r = br + dr, t1i = bi + di;
        xr[1][b] = t1r * c1 - t1i * s1;   xi[1][b] = t1r * s1 + t1i * c1;
        float t2r = ar - cr, t2i = ai - ci;
        xr[2][b] = t2r * c2 - t2i * s2;   xi[2][b] = t2r * s2 + t2i * c2;
        float t3r = br - dr, t3i = bi - di;
        xr[3][b] = t3r * c3 - t3i * s3;   xi[3][b] = t3r * s3 + t3i * c3;
    }
    {
        float e1c = cj * cj - sj * sj, e1s = 2.f * cj * sj;      // W^{2j}
        float c1 = e1c * e1c - e1s * e1s, s1 = 2.f * e1c * e1s;  // W^{4j}
        float c2 = c1 * c1 - s1 * s1, s2 = 2.f * c1 * s1;
        float c3 = c2 * c1 - s2 * s1, s3 = c2 * s1 + s2 * c1;
#pragma unroll
        for (int a = 0; a < 4; ++a) {
            float ar = xr[a][0] + xr[a][2], ai = xi[a][0] + xi[a][2];
            float br = xr[a][0] - xr[a][2], bi = xi[a][0] - xi[a][2];
            float cr = xr[a][1] + xr[a][3], ci = xi[a][1] + xi[a][3];
            float dr = xi[a][1] - xi[a][3], di = -(xr[a][1] - xr[a][3]);
            xr[a][0] = ar + cr;               xi[a][0] = ai + ci;
            float t1r = br + dr, t1i = bi + di;
            xr[a][1] = t1r * c1 - t1i * s1;   xi[a][1] = t1r * s1 + t1i * c1;
            float t2r = ar - cr, t2i = ai - ci;
            xr[a][2] = t2r * c2 - t2i * s2;   xi[a][2] = t2r * s2 + t2i * c2;
            float t3r = br - dr, t3i = bi - di;
            xr[a][3] = t3r * c3 - t3i * s3;   xi[a][3] = t3r * s3 + t3i * c3;
        }
    }
#pragma unroll
    for (int a = 0; a < 4; ++a)
#pragma unroll
        for (int b = 0; b < 4; ++b) {
            int idx = PIDX(base + a * (M >> 2) + b * Q);
            re[idx] = xr[a][b]; im[idx] = xi[a][b];
        }
}

template<int M>
__device__ inline void pass16_inv(float* re, float* im, int tid)
{
    const int Q = M >> 4;
    const int j = tid & (Q - 1);
    const int G = tid / Q;
    const int base = G * M + j;
    const float KR[4] = {1.f, 0.9238795325f, 0.7071067812f, 0.3826834324f};
    const float KI[4] = {0.f, 0.3826834324f, 0.7071067812f, 0.9238795325f};   // conj
    float xr[4][4], xi[4][4];
#pragma unroll
    for (int a = 0; a < 4; ++a)
#pragma unroll
        for (int b = 0; b < 4; ++b) {
            int idx = PIDX(base + a * (M >> 2) + b * Q);
            xr[a][b] = re[idx]; xi[a][b] = im[idx];
        }
    float cj, sj;
    __sincosf(6.283185307179586f / (float)M * (float)j, &sj, &cj);
    {
        float e1c = cj * cj - sj * sj, e1s = 2.f * cj * sj;
        float c1 = e1c * e1c - e1s * e1s, s1 = 2.f * e1c * e1s;
        float c2 = c1 * c1 - s1 * s1, s2 = 2.f * c1 * s1;
        float c3 = c2 * c1 - s2 * s1, s3 = c2 * s1 + s2 * c1;
#pragma unroll
        for (int a = 0; a < 4; ++a) {
            float t0r = xr[a][0], t0i = xi[a][0];
            float t1r = xr[a][1] * c1 - xi[a][1] * s1, t1i = xr[a][1] * s1 + xi[a][1] * c1;
            float t2r = xr[a][2] * c2 - xi[a][2] * s2, t2i = xr[a][2] * s2 + xi[a][2] * c2;
            float t3r = xr[a][3] * c3 - xi[a][3] * s3, t3i = xr[a][3] * s3 + xi[a][3] * c3;
            float pr = t0r + t2r, pi = t0i + t2i;
            float qr = t0r - t2r, qi = t0i - t2i;
            float rr = t1r + t3r, ri = t1i + t3i;
            float sr = -(t1i - t3i), si = t1r - t3r;
            xr[a][0] = pr + rr; xi[a][0] = pi + ri;
            xr[a][1] = qr + sr; xi[a][1] = qi + si;
            xr[a][2] = pr - rr; xi[a][2] = pi - ri;
            xr[a][3] = qr - sr; xi[a][3] = qi - si;
        }
    }
#pragma unroll
    for (int b = 0; b < 4; ++b) {
        float c1 = cj * KR[b] - sj * KI[b];
        float s1 = cj * KI[b] + sj * KR[b];
        float c2 = c1 * c1 - s1 * s1, s2 = 2.f * c1 * s1;
        float c3 = c2 * c1 - s2 * s1, s3 = c2 * s1 + s2 * c1;
        float t0r = xr[0][b], t0i = xi[0][b];
        float t1r = xr[1][b] * c1 - xi[1][b] * s1, t1i = xr[1][b] * s1 + xi[1][b] * c1;
        float t2r = xr[2][b] * c2 - xi[2][b] * s2, t2i = xr[2][b] * s2 + xi[2][b] * c2;
        float t3r = xr[3][b] * c3 - xi[3][b] * s3, t3i = xr[3][b] * s3 + xi[3][b] * c3;
        float pr = t0r + t2r, pi = t0i + t2i;
        float qr = t0r - t2r, qi = t0i - t2i;
        float rr = t1r + t3r, ri = t1i + t3i;
        float sr = -(t1i - t3i), si = t1r - t3r;
        xr[0][b] = pr + rr; xi[0][b] = pi + ri;
        xr[1][b] = qr + sr; xi[1][b] = qi + si;
        xr[2][b] = pr - rr; xi[2][b] = pi - ri;
        xr[3][b] = qr - sr; xi[3][b] = qi - si;
    }
#pragma unroll
    for (int a = 0; a < 4; ++a)
#pragma unroll
        for (int b = 0; b < 4; ++b) {
            int idx = PIDX(base + a * (M >> 2) + b * Q);
            re[idx] = xr[a][b]; im[idx] = xi[a][b];
        }
}

// ======= radix-8 tail (stage m=8 + r2), contiguous 8 points, constant twiddles =======
__device__ inline void fwd8(float* zr, float* zi, int o)
{
    const float R = 0.70710678118654752f;
    {
        float ar = zr[o] + zr[o+4], ai = zi[o] + zi[o+4];
        float br = zr[o] - zr[o+4], bi = zi[o] - zi[o+4];
        float cr = zr[o+2] + zr[o+6], ci = zi[o+2] + zi[o+6];
        float dr = zi[o+2] - zi[o+6], di = -(zr[o+2] - zr[o+6]);
        zr[o]   = ar + cr; zi[o]   = ai + ci;
        zr[o+2] = br + dr; zi[o+2] = bi + di;
        zr[o+4] = ar - cr; zi[o+4] = ai - ci;
        zr[o+6] = br - dr; zi[o+6] = bi - di;
    }
    {
        float ar = zr[o+1] + zr[o+5], ai = zi[o+1] + zi[o+5];
        float br = zr[o+1] - zr[o+5], bi = zi[o+1] - zi[o+5];
        float cr = zr[o+3] + zr[o+7], ci = zi[o+3] + zi[o+7];
        float dr = zi[o+3] - zi[o+7], di = -(zr[o+3] - zr[o+7]);
        zr[o+1] = ar + cr; zi[o+1] = ai + ci;
        float t1r = br + dr, t1i = bi + di;
        zr[o+3] = R * (t1r + t1i); zi[o+3] = R * (t1i - t1r);
        float t2r = ar - cr, t2i = ai - ci;
        zr[o+5] = t2i;  zi[o+5] = -t2r;
        float t3r = br - dr, t3i = bi - di;
        zr[o+7] = R * (t3i - t3r); zi[o+7] = -R * (t3r + t3i);
    }
#pragma unroll
    for (int p = 0; p < 8; p += 2) {
        float ur = zr[o+p], ui = zi[o+p], vr = zr[o+p+1], vi = zi[o+p+1];
        zr[o+p]   = ur + vr; zi[o+p]   = ui + vi;
        zr[o+p+1] = ur - vr; zi[o+p+1] = ui - vi;
    }
}

__device__ inline void inv8(float* zr, float* zi, int o)
{
    const float R = 0.70710678118654752f;
#pragma unroll
    for (int p = 0; p < 8; p += 2) {
        float ur = zr[o+p], ui = zi[o+p], vr = zr[o+p+1], vi = zi[o+p+1];
        zr[o+p]   = ur + vr; zi[o+p]   = ui + vi;
        zr[o+p+1] = ur - vr; zi[o+p+1] = ui - vi;
    }
    {
        float t0r = zr[o],   t0i = zi[o];
        float t1r = zr[o+2], t1i = zi[o+2];
        float t2r = zr[o+4], t2i = zi[o+4];
        float t3r = zr[o+6], t3i = zi[o+6];
        float pr = t0r + t2r, pi = t0i + t2i;
        float qr = t0r - t2r, qi = t0i - t2i;
        float rr = t1r + t3r, ri = t1i + t3i;
        float sr = -(t1i - t3i), si = t1r - t3r;
        zr[o]   = pr + rr; zi[o]   = pi + ri;
        zr[o+2] = qr + sr; zi[o+2] = qi + si;
        zr[o+4] = pr - rr; zi[o+4] = pi - ri;
        zr[o+6] = qr - sr; zi[o+6] = qi - si;
    }
    {
        float t0r = zr[o+1], t0i = zi[o+1];
        float yr = zr[o+3], yi = zi[o+3];
        float t1r = R * (yr - yi), t1i = R * (yr + yi);
        yr = zr[o+5]; yi = zi[o+5];
        float t2r = -yi, t2i = yr;
        yr = zr[o+7]; yi = zi[o+7];
        float t3r = -R * (yr + yi), t3i = R * (yr - yi);
        float pr = t0r + t2r, pi = t0i + t2i;
        float qr = t0r - t2r, qi = t0i - t2i;
        float rr = t1r + t3r, ri = t1i + t3i;
        float sr = -(t1i - t3i), si = t1r - t3r;
        zr[o+1] = pr + rr; zi[o+1] = pi + ri;
        zr[o+3] = qr + sr; zi[o+3] = qi + si;
        zr[o+5] = pr - rr; zi[o+5] = pi - ri;
        zr[o+7] = qr - sr; zi[o+7] = qi - si;
    }
}

// ============ prep: [blocks 0..255] RPE (32 pos/block) -> a_t
//              [blocks 256..767] transpose x -> xt2 ============
// LESSON R8-R10 (firm): per-thread acc arrays > ~16 floats get spilled by the
// occupancy-greedy allocator (R10: acc[8][8] with VGPR_Count=60 -> 64KB/thread
// scratch = 70us). Keep register tiles <= 16; win parallelism with blocks.
// Hidden: thread = 1 pos x 8 feats (acc 8). Out: thread = 4 pos x 4 outs
// (acc 16), 4 chunk-rounds. Activations via LDS b128 (transposed ubuf[j][pos],
// stride 36 = 16B-aligned, 2-way banks free); weights via VMEM (separate pipe).
__global__ __launch_bounds__(256, 2) void prep_kernel(
    const float* __restrict__ x,
    const float* __restrict__ w_in, const float* __restrict__ b_in,
    const float* __restrict__ w_hid, const float* __restrict__ b_hid,
    const float* __restrict__ w_out, const float* __restrict__ b_out,
    float* __restrict__ a_t, float2* __restrict__ xt2)
{
    __shared__ __align__(16) char smem[33536];
    const int tid = threadIdx.x;

    if (blockIdx.x >= 256) {
        // ---- transpose x: (2,8,N,64) -> xt2[hd][n] = (x_b0, x_b1) ----
        float (*t0)[65] = (float (*)[65])smem;
        float (*t1)[65] = (float (*)[65])(smem + 16640);
        int bb = blockIdx.x - 256;
        int h = bb >> 6;
        int nb = bb & 63;
        int lx = tid & 63;
        int ly = tid >> 6;          // 0..3
        const float* s0 = x + ((size_t)h * N_SEQ + nb * 64) * 64;
        const float* s1 = x + ((size_t)(8 + h) * N_SEQ + nb * 64) * 64;
        for (int r = ly; r < 64; r += 4) {
            t0[r][lx] = s0[r * 64 + lx];
            t1[r][lx] = s1[r * 64 + lx];
        }
        __syncthreads();
        for (int r = ly; r < 64; r += 4) {
            float2* dst = xt2 + (size_t)(h * 64 + r) * N_SEQ + nb * 64;
            dst[lx] = make_float2(t0[lx][r], t1[lx][r]);
        }
        return;
    }

    // LDS: ubuf[j=64][pos stride 36] transposed activations (9216 B);
    //      sums[pos=32][9] RMS partials (1152 B)
    float (*ubuf)[36] = (float (*)[36])smem;
    float (*sums)[9]  = (float (*)[9])(smem + 9216);
    const int pos0 = blockIdx.x * 32;

    // ---- hidden chain: thread = (p = tid&31, fp = tid>>5 -> feats fp*8..+7) ----
    {
        const int p  = tid & 31;
        const int fp = tid >> 5;
        const int pos = pos0 + p;
        float v;
        if (pos == 0 || pos == N_SEQ) v = 1.0f;
        else if (pos < N_SEQ)         v = 1.0f / (float)(pos + 1);
        else                          v = -1.0f / (float)(2 * N_SEQ + 1 - pos);

        float h[8];
#pragma unroll
        for (int i = 0; i < 8; ++i) {
            int f = fp * 8 + i;
            h[i] = v * w_in[f] + b_in[f];
        }
        for (int L = 0; L <= LAYERS; ++L) {
            float s = 0.f;
#pragma unroll
            for (int i = 0; i < 8; ++i) s += h[i] * h[i];
            sums[p][fp] = s;
            __syncthreads();          // also orders prior j-loop's ubuf reads
            float tot = 0.f;
#pragma unroll
            for (int g = 0; g < 8; ++g) tot += sums[p][g];
            float r = rsqrtf(tot * (1.f / 64.f) + 1e-8f);
#pragma unroll
            for (int i = 0; i < 8; ++i)
                ubuf[fp * 8 + i][p] = fmaxf(h[i] * r, 0.f);   // transposed [j][pos]
            __syncthreads();
            if (L == LAYERS) break;
            float acc[8];
#pragma unroll
            for (int i = 0; i < 8; ++i) acc[i] = b_hid[L * 64 + fp * 8 + i];
            const float* wb = w_hid + L * 4096 + fp * 8;
#pragma unroll 4
            for (int j = 0; j < 64; ++j) {
                float uj = ubuf[j][p];
                float4 w0 = *(const float4*)(wb + j * 64);
                float4 w1 = *(const float4*)(wb + j * 64 + 4);
                acc[0] = fmaf(uj, w0.x, acc[0]); acc[1] = fmaf(uj, w0.y, acc[1]);
                acc[2] = fmaf(uj, w0.z, acc[2]); acc[3] = fmaf(uj, w0.w, acc[3]);
                acc[4] = fmaf(uj, w1.x, acc[4]); acc[5] = fmaf(uj, w1.y, acc[5]);
                acc[6] = fmaf(uj, w1.z, acc[6]); acc[7] = fmaf(uj, w1.w, acc[7]);
            }
#pragma unroll
            for (int i = 0; i < 8; ++i) h[i] = acc[i];
        }
    }

    // ---- out GEMM: thread = (p4 = tid&7 -> pos p4*4..+3, of = tid>>3 -> outs of*4..+3)
    //      4 rounds of 128 outputs; acc[4][4] = 16 regs (no spill) ----
    {
        const int p4 = tid & 7;
        const int of = tid >> 3;
        for (int co = 0; co < 4; ++co) {
            float acc[4][4];          // [out i][pos k]
#pragma unroll
            for (int i = 0; i < 4; ++i) {
                float bo = b_out[co * 128 + of * 4 + i];
#pragma unroll
                for (int k = 0; k < 4; ++k) acc[i][k] = bo;
            }
            const float* wb = w_out + co * 128 + of * 4;
#pragma unroll 4
            for (int j = 0; j < 64; ++j) {
                float4 u4 = *(const float4*)&ubuf[j][p4 * 4];
                float4 w4 = *(const float4*)(wb + j * 512);
                acc[0][0] = fmaf(u4.x, w4.x, acc[0][0]); acc[0][1] = fmaf(u4.y, w4.x, acc[0][1]);
                acc[0][2] = fmaf(u4.z, w4.x, acc[0][2]); acc[0][3] = fmaf(u4.w, w4.x, acc[0][3]);
                acc[1][0] = fmaf(u4.x, w4.y, acc[1][0]); acc[1][1] = fmaf(u4.y, w4.y, acc[1][1]);
                acc[1][2] = fmaf(u4.z, w4.y, acc[1][2]); acc[1][3] = fmaf(u4.w, w4.y, acc[1][3]);
                acc[2][0] = fmaf(u4.x, w4.z, acc[2][0]); acc[2][1] = fmaf(u4.y, w4.z, acc[2][1]);
                acc[2][2] = fmaf(u4.z, w4.z, acc[2][2]); acc[2][3] = fmaf(u4.w, w4.z, acc[2][3]);
                acc[3][0] = fmaf(u4.x, w4.w, acc[3][0]); acc[3][1] = fmaf(u4.y, w4.w, acc[3][1]);
                acc[3][2] = fmaf(u4.z, w4.w, acc[3][2]); acc[3][3] = fmaf(u4.w, w4.w, acc[3][3]);
            }
#pragma unroll
            for (int i = 0; i < 4; ++i) {
                float* dst = a_t + (size_t)(co * 128 + of * 4 + i) * N_FFT + pos0 + p4 * 4;
                *(float4*)dst = make_float4(acc[i][0], acc[i][1], acc[i][2], acc[i][3]);
            }
        }
    }
}

// ========== conv: A-FFT (spectrum kept in regs) + z-FFT + mult + iFFT ==========
__global__ __launch_bounds__(FT, 2) void conv_kernel(const float* __restrict__ a_t,
                                                     const float2* __restrict__ xt2,
                                                     float2* __restrict__ out_t2)
{
    __shared__ float re[8448];
    __shared__ float im[8448];
    const int tid = threadIdx.x;
    const int hd = blockIdx.x;
    const float JR = 0.9238795325f;        // e^{-2pi i/16}
    const float JI = -0.3826834324f;

    // ---- A forward: fused m=8192 stage (real input) ----
    {
        const float* src = a_t + (size_t)hd * N_FFT;
        float ck, sk;
        __sincosf(-6.283185307179586f / 8192.f * (float)tid, &sk, &ck);
#pragma unroll
        for (int pp = 0; pp < 4; ++pp) {
            int k = pp * FT + tid;
            float x0 = src[k], x1 = src[k + 2048], x2 = src[k + 4096], x3 = src[k + 6144];
            float ar = x0 + x2, br = x0 - x2;
            float cr = x1 + x3, e = x1 - x3;
            re[PIDX(k)] = ar + cr; im[PIDX(k)] = 0.f;
            float c1 = ck, s1 = sk;
            float c2 = c1 * c1 - s1 * s1, s2 = 2.f * c1 * s1;
            float c3 = c2 * c1 - s2 * s1, s3 = c2 * s1 + s2 * c1;
            re[PIDX(k + 2048)] = br * c1 + e * s1;  im[PIDX(k + 2048)] = br * s1 - e * c1;
            float t2r = ar - cr;
            re[PIDX(k + 4096)] = t2r * c2;          im[PIDX(k + 4096)] = t2r * s2;
            re[PIDX(k + 6144)] = br * c3 - e * s3;  im[PIDX(k + 6144)] = br * s3 + e * c3;
            float tc = ck * JR - sk * JI; sk = ck * JI + sk * JR; ck = tc;  // W^{k+512}
        }
    }
    __syncthreads();
    pass16_fwd<2048>(re, im, tid);
    __syncthreads();
    pass16_fwd<128>(re, im, tid);
    __syncthreads();
    // ---- A tail: unscaled spectrum stays in registers (1/N folded in later) ----
    float afr[16], afi[16];
    {
        const int base = tid * 16;
#pragma unroll
        for (int c = 0; c < 16; ++c) { int idx = PIDX(base + c); afr[c] = re[idx]; afi[c] = im[idx]; }
        fwd8(afr, afi, 0); fwd8(afr, afi, 8);
    }
    __syncthreads();
    // ---- Z forward: fused m=8192 stage (packed complex, x2=x3=0) ----
    {
        const float2* src = xt2 + (size_t)hd * N_SEQ;
        float ck, sk;
        __sincosf(-6.283185307179586f / 8192.f * (float)tid, &sk, &ck);
#pragma unroll
        for (int pp = 0; pp < 4; ++pp) {
            int k = pp * FT + tid;
            float2 z0 = src[k], z1 = src[k + 2048];
            float ar = z0.x, ai = z0.y;
            float cr = z1.x, ci = z1.y;
            float dr = z1.y, di = -z1.x;
            re[PIDX(k)] = ar + cr; im[PIDX(k)] = ai + ci;
            float c1 = ck, s1 = sk;
            float c2 = c1 * c1 - s1 * s1, s2 = 2.f * c1 * s1;
            float c3 = c2 * c1 - s2 * s1, s3 = c2 * s1 + s2 * c1;
            float t1r = ar + dr, t1i = ai + di;
            re[PIDX(k + 2048)] = t1r * c1 - t1i * s1; im[PIDX(k + 2048)] = t1r * s1 + t1i * c1;
            float t2r = ar - cr, t2i = ai - ci;
            re[PIDX(k + 4096)] = t2r * c2 - t2i * s2; im[PIDX(k + 4096)] = t2r * s2 + t2i * c2;
            float t3r = ar - dr, t3i = ai - di;
            re[PIDX(k + 6144)] = t3r * c3 - t3i * s3; im[PIDX(k + 6144)] = t3r * s3 + t3i * c3;
            float tc = ck * JR - sk * JI; sk = ck * JI + sk * JR; ck = tc;
        }
    }
    __syncthreads();
    pass16_fwd<2048>(re, im, tid);
    __syncthreads();
    pass16_fwd<128>(re, im, tid);
    __syncthreads();
    {   // Z tail + pointwise (af in regs, 1/N fused) + inverse head
        const int base = tid * 16;
        float zr[16], zi[16];
#pragma unroll
        for (int c = 0; c < 16; ++c) { int idx = PIDX(base + c); zr[c] = re[idx]; zi[c] = im[idx]; }
        fwd8(zr, zi, 0); fwd8(zr, zi, 8);
        const float inv = 1.0f / (float)N_FFT;
#pragma unroll
        for (int c = 0; c < 16; ++c) {
            float xr = zr[c], xi_ = zi[c];
            zr[c] = (xr * afr[c] - xi_ * afi[c]) * inv;
            zi[c] = (xr * afi[c] + xi_ * afr[c]) * inv;
        }
        inv8(zr, zi, 0); inv8(zr, zi, 8);
#pragma unroll
        for (int c = 0; c < 16; ++c) { int idx = PIDX(base + c); re[idx] = zr[c]; im[idx] = zi[c]; }
    }
    __syncthreads();
    pass16_inv<128>(re, im, tid);
    __syncthreads();
    pass16_inv<2048>(re, im, tid);
    __syncthreads();
    {   // fused final inverse stage (m=8192): store only [0,4096)
        float2* dst = out_t2 + (size_t)hd * N_SEQ;
        float ck, sk;
        __sincosf(6.283185307179586f / 8192.f * (float)tid, &sk, &ck);
        const float JcR = 0.9238795325f, JcI = 0.3826834324f;
#pragma unroll
        for (int pp = 0; pp < 4; ++pp) {
            int k = pp * FT + tid;
            float c1 = ck, s1 = sk;
            float c2 = c1 * c1 - s1 * s1, s2 = 2.f * c1 * s1;
            float c3 = c2 * c1 - s2 * s1, s3 = c2 * s1 + s2 * c1;
            float t0r = re[PIDX(k)],        t0i = im[PIDX(k)];
            float y1r = re[PIDX(k + 2048)], y1i = im[PIDX(k + 2048)];
            float y2r = re[PIDX(k + 4096)], y2i = im[PIDX(k + 4096)];
            float y3r = re[PIDX(k + 6144)], y3i = im[PIDX(k + 6144)];
            float t1r = y1r * c1 - y1i * s1, t1i = y1r * s1 + y1i * c1;
            float t2r = y2r * c2 - y2i * s2, t2i = y2r * s2 + y2i * c2;
            float t3r = y3r * c3 - y3i * s3, t3i = y3r * s3 + y3i * c3;
            float pr = t0r + t2r, pi = t0i + t2i;
            float qr = t0r - t2r, qi = t0i - t2i;
            float rr = t1r + t3r, ri = t1i + t3i;
            float sr = -(t1i - t3i), si = t1r - t3r;
            dst[k]        = make_float2(pr + rr, pi + ri);
            dst[k + 2048] = make_float2(qr + sr, qi + si);
            float tc = ck * JcR - sk * JcI; sk = ck * JcI + sk * JcR; ck = tc;
        }
    }
}

// ========== transpose out: out_t2[hd][n] -> out (2,8,N,64) ==========
__global__ __launch_bounds__(256) void transpose_o_kernel(const float2* __restrict__ out_t2,
                                                          float* __restrict__ out)
{
    __shared__ float t0[64][65];
    __shared__ float t1[64][65];
    int h = blockIdx.x >> 6;
    int nb = blockIdx.x & 63;
    int lx = threadIdx.x & 63;
    int ly = threadIdx.x >> 6;
    for (int r = ly; r < 64; r += 4) {
        float2 v = out_t2[(size_t)(h * 64 + r) * N_SEQ + nb * 64 + lx];
        t0[r][lx] = v.x;
        t1[r][lx] = v.y;
    }
    __syncthreads();
    float* d0 = out + ((size_t)h * N_SEQ + nb * 64) * 64;
    float* d1 = out + ((size_t)(8 + h) * N_SEQ + nb * 64) * 64;
    for (int r = ly; r < 64; r += 4) {
        d0[r * 64 + lx] = t0[lx][r];
        d1[r * 64 + lx] = t1[lx][r];
    }
}

extern "C" void kernel_launch(void* const* d_in, const int* in_sizes, int n_in,
                              void* d_out, int out_size, void* d_ws, size_t ws_size,
                              hipStream_t stream)
{
    const float* x     = (const float*)d_in[0];
    const float* w_in  = (const float*)d_in[1];
    const float* b_in  = (const float*)d_in[2];
    const float* w_hid = (const float*)d_in[3];
    const float* b_hid = (const float*)d_in[4];
    const float* w_out = (const float*)d_in[5];
    const float* b_out = (const float*)d_in[6];
    float* out = (float*)d_out;

    char* ws = (char*)d_ws;
    float2* xt2    = (float2*)ws;                               // 16 MB
    float*  a_t    = (float*)(ws + (size_t)16 * 1024 * 1024);   // 16 MB
    float2* out_t2 = (float2*)(ws + (size_t)32 * 1024 * 1024);  // 16 MB

    prep_kernel<<<768, 256, 0, stream>>>(x, w_in, b_in, w_hid, b_hid, w_out, b_out,
                                         a_t, xt2);
    conv_kernel<<<512, FT, 0, stream>>>(a_t, xt2, out_t2);
    transpose_o_kernel<<<512, 256, 0, stream>>>(out_t2, out);
}